// Round 7
// baseline (155.340 us; speedup 1.0000x reference)
//
#include <hip/hip_runtime.h>

typedef unsigned short u16;
typedef unsigned int u32;
typedef __attribute__((ext_vector_type(4))) float f32x4;
typedef __attribute__((ext_vector_type(8))) short short8;

#define HWD 56
#define HW2 3136
#define C_IN 128
#define K_OUT 256
#define N_IMG 32
#define CHW_IN 401408   // 128*3136
#define PIX 100352      // 32*3136
#define WQ_N 294912     // 256*128*9
// xt2 layout: [n][hp58][cq4][wp58][c32] bf16 ; per (n,hp,cq) region = 58*32 = 1856 elems
#define X2_ROW 1856
#define X2_H 7424       // 4*1856
#define X2_N 430592     // 58*7424
#define NSLICE 1568     // 784 nt * 2 wn
#define CV_OFF 33554432u            // cvout offset in ws (32MB)
#define WS_NEED_BF16 (CV_OFF + (size_t)PIX * K_OUT * 2)

__device__ __forceinline__ u16 f2bf(float f) {
    u32 u = __float_as_uint(f);
    u32 r = u + 0x7FFFu + ((u >> 16) & 1u);
    return (u16)(r >> 16);
}

__device__ __forceinline__ void glds16(const u16* g, u16* l) {
    __builtin_amdgcn_global_load_lds(
        (const __attribute__((address_space(1))) void*)g,
        (__attribute__((address_space(3))) void*)l, 16, 0, 0);
}

__global__ void maxabs_k(const float* __restrict__ w, u32* __restrict__ wsmax) {
    float m = 0.f;
    for (int i = blockIdx.x * blockDim.x + threadIdx.x; i < WQ_N; i += gridDim.x * blockDim.x)
        m = fmaxf(m, fabsf(w[i]));
    for (int off = 32; off; off >>= 1)
        m = fmaxf(m, __shfl_xor(m, off));
    __shared__ float sm[4];
    int lane = threadIdx.x & 63, wid = threadIdx.x >> 6;
    if (lane == 0) sm[wid] = m;
    __syncthreads();
    if (threadIdx.x == 0) {
        float mm = fmaxf(fmaxf(sm[0], sm[1]), fmaxf(sm[2], sm[3]));
        atomicMax(wsmax, __float_as_uint(mm));
    }
}

// wqt3 layout: [kt(36)][mt(2)][oct(4)][m(128)][8] — contiguous 8KB A-tile per (kt,mt).
// kt = tap*4 + cq ; c = cq*32 + oct*8 + j ; m = mt*128 + mrow
__global__ void quant_t_k3(const float* __restrict__ w, const u32* __restrict__ wsmax,
                           u16* __restrict__ wqt3) {
    int o = blockIdx.x * 256 + threadIdx.x;
    if (o >= WQ_N) return;
    int j = o & 7;
    int r1 = o >> 3;
    int mrow = r1 & 127;
    int r2 = r1 >> 7;
    int oct = r2 & 3;
    int r3 = r2 >> 2;
    int mt = r3 & 1;
    int kt = r3 >> 1;
    int m = mt * 128 + mrow;
    int tap = kt >> 2, cq = kt & 3;
    int c = cq * 32 + oct * 8 + j;
    float scale = __uint_as_float(wsmax[0]) / 7.0f;
    float q = rintf(w[(m * 128 + c) * 9 + tap] / scale);
    q = fminf(fmaxf(q, -7.0f), 7.0f);
    wqt3[o] = f2bf(q * scale);
}

// zero only the 1-pixel halo of xt2
__global__ void halo_zero(u16* __restrict__ xt2) {
    int i = blockIdx.x * 256 + threadIdx.x;
    if (i >= 32 * 3648) return;
    int n = i / 3648, t = i - n * 3648;
    int site = t >> 4, c16 = t & 15;   // c16: 16B chunk of the 128 channels
    int h, w;
    if (site < 58)       { h = 0;          w = site; }
    else if (site < 116) { h = 57;         w = site - 58; }
    else if (site < 172) { h = site - 115; w = 0; }
    else                 { h = site - 171; w = 57; }
    int cq = c16 >> 2, o4 = c16 & 3;
    *(uint4*)(xt2 + (size_t)n * X2_N + h * X2_H + cq * X2_ROW + w * 32 + o4 * 8) =
        (uint4){0, 0, 0, 0};
}

// x (NCHW f32) -> xt2 interior
__global__ __launch_bounds__(256) void pad_transpose(const float* __restrict__ x,
                                                     u16* __restrict__ xt2) {
    __shared__ float T[128][57];
    const int tid = threadIdx.x;
    const int n = blockIdx.x / HWD;
    const int h = blockIdx.x - n * HWD;
    const float* src = x + (size_t)n * CHW_IN + h * HW2;  // row h of all channels? no:
    // src for channel c, col w: x[n][c][h][w] = n*CHW_IN + c*HW2 + h*HWD + w
    const float* srow = x + (size_t)n * CHW_IN + h * HWD;
    #pragma unroll
    for (int it = 0; it < 7; ++it) {
        int i = tid + it * 256;
        int c = i / 14, q = i - c * 14;
        float4 v = *(const float4*)(srow + c * HW2 + q * 4);
        T[c][q * 4 + 0] = v.x; T[c][q * 4 + 1] = v.y;
        T[c][q * 4 + 2] = v.z; T[c][q * 4 + 3] = v.w;
    }
    __syncthreads();
    u16* drow = xt2 + (size_t)n * X2_N + (h + 1) * X2_H;
    #pragma unroll
    for (int it = 0; it < 4; ++it) {
        int i = tid + it * 256;
        if (i < 56 * 16) {
            int w = i >> 4, oc = i & 15;
            int cq = oc >> 2, o4 = oc & 3;
            union { u16 us[8]; uint4 v4; } pk;
            #pragma unroll
            for (int j = 0; j < 8; ++j) pk.us[j] = f2bf(T[oc * 8 + j][w]);
            *(uint4*)(drow + cq * X2_ROW + (w + 1) * 32 + o4 * 8) = pk.v4;
        }
    }
}

// ===== BM128 x BN128 x BK32, 3-buf depth-2 counted-vmcnt, dense B staging =====
// grid 784 (one nt each), 2 mt passes per block -> tail 784/768 = 1.02 rounds.
// LDS buf: A [oct4][m128][8] + B [px128][oct4][8] = 16KB; 3 bufs = 48KB.
template <bool BF16OUT>
__global__ __launch_bounds__(256, 3) void conv_m(const u16* __restrict__ xt2,
                                                 const u16* __restrict__ wqt3,
                                                 float* __restrict__ out,
                                                 u16* __restrict__ cvout,
                                                 float* __restrict__ P) {
    __shared__ __align__(16) u16 lds[3][2][4096];   // 48 KB
    const int tid = threadIdx.x;
    const int lane = tid & 63;
    const int w4 = tid >> 6;           // 4 waves, 2m x 2n
    const int wm = w4 >> 1, wn = w4 & 1;
    const int fr = lane & 15, fq = lane >> 4;
    // XCD swizzle: 784 = 8*98, bijective
    const int nt = (blockIdx.x & 7) * 98 + (blockIdx.x >> 3);
    const int pixbase = nt * 128;

    // per-lane dense B sites: instr j covers px_local = w4*32 + j*16 + (l>>2), oct = l&3
    u32 siteL[2];
    #pragma unroll
    for (int j = 0; j < 2; ++j) {
        int p = pixbase + w4 * 32 + j * 16 + (lane >> 2);
        int n = p / HW2; int hw = p - n * HW2;
        int h = hw / HWD; int ww = hw - h * HWD;
        siteL[j] = (u32)(n * X2_N + h * X2_H + ww * 32 + (lane & 3) * 8);
    }

#define STAGE(AB, BB, kt_, mt_) do {                                              \
        const int tap_ = (kt_) >> 2, cq_ = (kt_) & 3;                             \
        const int r_ = tap_ / 3, s_ = tap_ - r_ * 3;                              \
        const u16* ga_ = wqt3 + ((kt_) * 2 + (mt_)) * 4096 + (w4 * 2) * 512 + lane * 8; \
        glds16(ga_,       (AB) + (w4 * 2 + 0) * 512);                             \
        glds16(ga_ + 512, (AB) + (w4 * 2 + 1) * 512);                             \
        const u32 D_ = (u32)((r_ * 4 + cq_) * X2_ROW + s_ * 32);                  \
        glds16(xt2 + siteL[0] + D_, (BB) + w4 * 1024 + 0);                        \
        glds16(xt2 + siteL[1] + D_, (BB) + w4 * 1024 + 512);                      \
    } while (0)
#define PHASE_BODY(Acur, Bcur) do {                                               \
        short8 af[4], bf[4];                                                      \
        _Pragma("unroll") for (int mi = 0; mi < 4; ++mi)                          \
            af[mi] = *(const short8*)&(Acur)[fq * 1024 + (wm * 64 + mi * 16 + fr) * 8]; \
        _Pragma("unroll") for (int ni = 0; ni < 4; ++ni)                          \
            bf[ni] = *(const short8*)&(Bcur)[(wn * 64 + ni * 16 + fr) * 32 + fq * 8]; \
        __builtin_amdgcn_s_setprio(1);                                            \
        _Pragma("unroll") for (int mi = 0; mi < 4; ++mi)                          \
            _Pragma("unroll") for (int ni = 0; ni < 4; ++ni)                      \
                acc[mi][ni] = __builtin_amdgcn_mfma_f32_16x16x32_bf16(            \
                    af[mi], bf[ni], acc[mi][ni], 0, 0, 0);                        \
        __builtin_amdgcn_s_setprio(0);                                            \
    } while (0)
#define BAR() __builtin_amdgcn_s_barrier()
#define SCHED0() __builtin_amdgcn_sched_barrier(0)
#define GATE(n_) asm volatile("s_waitcnt vmcnt(" #n_ ")" ::: "memory")

    f32x4 acc[4][4];

    #pragma unroll 1
    for (int mt = 0; mt < 2; ++mt) {
        #pragma unroll
        for (int a = 0; a < 4; ++a)
            #pragma unroll
            for (int b = 0; b < 4; ++b)
                acc[a][b] = (f32x4){0.f, 0.f, 0.f, 0.f};

        // prologue: tiles 0,1 into bufs 0,1; keep tile1's 4 in flight
        STAGE(&lds[0][0][0], &lds[0][1][0], 0, mt);
        STAGE(&lds[1][0][0], &lds[1][1][0], 1, mt);
        GATE(4);
        BAR();

        #pragma unroll 1
        for (int tt = 0; tt < 12; ++tt) {
            #pragma unroll
            for (int u = 0; u < 3; ++u) {
                const int t = tt * 3 + u;
                const int bs = (u + 2) % 3;
                SCHED0();
                if (t < 34) STAGE(&lds[bs][0][0], &lds[bs][1][0], t + 2, mt);
                PHASE_BODY(&lds[u][0][0], &lds[u][1][0]);
                SCHED0();
                if (t < 34) GATE(4);
                else if (t == 34) GATE(0);
                BAR();
            }
        }

        // ---- fused per-channel partials
        const int slice = nt * 2 + wn;
        #pragma unroll
        for (int mi = 0; mi < 4; ++mi)
            #pragma unroll
            for (int j = 0; j < 4; ++j) {
                float s = 0.f, q = 0.f;
                #pragma unroll
                for (int ni = 0; ni < 4; ++ni) {
                    float v = acc[mi][ni][j];
                    s += v; q += v * v;
                }
                #pragma unroll
                for (int msk = 1; msk < 16; msk <<= 1) {
                    s += __shfl_xor(s, msk);
                    q += __shfl_xor(q, msk);
                }
                if (fr == 0) {
                    int ch = mt * 128 + wm * 64 + mi * 16 + fq * 4 + j;
                    float* dst = P + ((size_t)ch * NSLICE + slice) * 2;
                    dst[0] = s; dst[1] = q;
                }
            }

        if (BF16OUT) {
            // dense epilogue: LDS transpose to T[ch128][px 136pad], 16B stores
            u16* T = (u16*)&lds[0][0][0];        // 34816 B of the 48KB
            #pragma unroll
            for (int mi = 0; mi < 4; ++mi)
                #pragma unroll
                for (int ni = 0; ni < 4; ++ni) {
                    int px_l = wn * 64 + ni * 16 + fr;
                    int ch_l = wm * 64 + mi * 16 + fq * 4;
                    #pragma unroll
                    for (int j = 0; j < 4; ++j)
                        T[(ch_l + j) * 136 + px_l] = f2bf(acc[mi][ni][j]);
                }
            __syncthreads();
            #pragma unroll
            for (int it = 0; it < 8; ++it) {
                int q = tid + it * 256;
                int ch_l = q >> 4, pg = q & 15;
                uint4 v = *(const uint4*)&T[ch_l * 136 + pg * 8];
                *(uint4*)&cvout[(size_t)(mt * 128 + ch_l) * PIX + pixbase + pg * 8] = v;
            }
            __syncthreads();   // T reads done before next pass overwrites LDS
        } else {
            #pragma unroll
            for (int ni = 0; ni < 4; ++ni) {
                int pix = pixbase + wn * 64 + ni * 16 + fr;
                int n = pix / HW2;
                int hw = pix - n * HW2;
                size_t obase = (size_t)n * (K_OUT * HW2) + hw;
                #pragma unroll
                for (int mi = 0; mi < 4; ++mi) {
                    int ch = mt * 128 + wm * 64 + mi * 16 + fq * 4;
                    #pragma unroll
                    for (int j = 0; j < 4; ++j)
                        out[obase + (size_t)(ch + j) * HW2] = acc[mi][ni][j];
                }
            }
            __syncthreads();
        }
    }
#undef STAGE
#undef PHASE_BODY
#undef BAR
#undef SCHED0
#undef GATE
}

__global__ void stats_fin(const float* __restrict__ P, const float* __restrict__ gamma,
                          const float* __restrict__ beta, float* __restrict__ stats) {
    int ch = blockIdx.x;
    int tid = threadIdx.x;
    float s = 0.f, q = 0.f;
    const float* base = P + (size_t)ch * NSLICE * 2;
    for (int i = tid; i < NSLICE; i += 256) {
        float2 v = *(const float2*)(base + i * 2);
        s += v.x; q += v.y;
    }
    for (int m = 32; m; m >>= 1) { s += __shfl_xor(s, m); q += __shfl_xor(q, m); }
    __shared__ float ss[4], qs[4];
    int l = tid & 63, w = tid >> 6;
    if (l == 0) { ss[w] = s; qs[w] = q; }
    __syncthreads();
    if (tid == 0) {
        float S = ss[0] + ss[1] + ss[2] + ss[3];
        float Q = qs[0] + qs[1] + qs[2] + qs[3];
        float mean = S / (float)PIX;
        float var = Q / (float)PIX - mean * mean;
        float inv = gamma[ch] * rsqrtf(var + 1e-5f);
        stats[2 * ch] = inv;
        stats[2 * ch + 1] = beta[ch] - mean * inv;
    }
}

// cvout [ch][global-pix] bf16 -> out NCHW f32 (both sides dense)
__global__ void bn_relu_nchw(const u16* __restrict__ cvout, float* __restrict__ out,
                             const float* __restrict__ stats) {
    const int b = blockIdx.x;            // 256 ch * 49 groups
    const int ch = b / 49, g = b - ch * 49;
    const float inv = stats[2 * ch], sh = stats[2 * ch + 1];
    const int p8 = (g * 256 + threadIdx.x) * 8;
    short8 v = *(const short8*)&cvout[(size_t)ch * PIX + p8];
    const int n = p8 / HW2;
    const int hw = p8 - n * HW2;
    float* dst = out + ((size_t)n * K_OUT + ch) * HW2 + hw;
    f32x4 o0, o1;
    #pragma unroll
    for (int j = 0; j < 4; ++j) {
        float a = __uint_as_float(((u32)(u16)v[j]) << 16);
        float bb = __uint_as_float(((u32)(u16)v[j + 4]) << 16);
        o0[j] = fmaxf(a * inv + sh, 0.f);
        o1[j] = fmaxf(bb * inv + sh, 0.f);
    }
    *(f32x4*)dst = o0;
    *(f32x4*)(dst + 4) = o1;
}

__global__ void bn_relu_f32(float* __restrict__ out, const float* __restrict__ stats) {
    const int n4 = ((size_t)N_IMG * K_OUT * HW2) / 4;
    int stride = gridDim.x * blockDim.x;
    for (int i = blockIdx.x * blockDim.x + threadIdx.x; i < n4; i += stride) {
        int ch = (i / (HW2 / 4)) & (K_OUT - 1);
        float inv = stats[2 * ch], sh = stats[2 * ch + 1];
        f32x4 v = ((f32x4*)out)[i];
        #pragma unroll
        for (int j = 0; j < 4; ++j)
            v[j] = fmaxf(v[j] * inv + sh, 0.f);
        ((f32x4*)out)[i] = v;
    }
}

extern "C" void kernel_launch(void* const* d_in, const int* in_sizes, int n_in,
                              void* d_out, int out_size, void* d_ws, size_t ws_size,
                              hipStream_t stream) {
    const float* x = (const float*)d_in[0];
    const float* w = (const float*)d_in[1];
    const float* gamma = (const float*)d_in[2];
    const float* beta = (const float*)d_in[3];
    float* out = (float*)d_out;

    char* ws = (char*)d_ws;
    u32* wsmax = (u32*)ws;                         // [0, 64)
    float* stats = (float*)(ws + 64);              // 2KB
    u16* wqt3 = (u16*)(ws + 4096);                 // 589,824 B
    u16* xt2 = (u16*)(ws + (1u << 20));            // 27,557,888 B
    float* P = (float*)(ws + 29360128u);           // 3,211,264 B (ends 32.57MB)
    u16* cvout = (u16*)(ws + CV_OFF);              // 51,380,224 B
    const bool bf16path = (ws_size >= WS_NEED_BF16);

    hipMemsetAsync(wsmax, 0, 64, stream);
    maxabs_k<<<128, 256, 0, stream>>>(w, wsmax);
    quant_t_k3<<<WQ_N / 256, 256, 0, stream>>>(w, wsmax, wqt3);
    halo_zero<<<456, 256, 0, stream>>>(xt2);
    pad_transpose<<<N_IMG * HWD, 256, 0, stream>>>(x, xt2);
    if (bf16path) {
        conv_m<true><<<784, 256, 0, stream>>>(xt2, wqt3, out, cvout, P);
        stats_fin<<<K_OUT, 256, 0, stream>>>(P, gamma, beta, stats);
        bn_relu_nchw<<<K_OUT * 49, 256, 0, stream>>>(cvout, out, stats);
    } else {
        conv_m<false><<<784, 256, 0, stream>>>(xt2, wqt3, out, cvout, P);
        stats_fin<<<K_OUT, 256, 0, stream>>>(P, gamma, beta, stats);
        bn_relu_f32<<<4096, 256, 0, stream>>>(out, stats);
    }
}